// Round 17
// baseline (29.816 us; speedup 1.0000x reference)
//
#include <hip/hip_runtime.h>

// CTC batch cost, forward-backward split, f32 probability domain with
// PER-LANE power-of-2 scaling (exact; proven in round 9, absmax 0.0),
// combined with round-16's structure: off-chain per-16-step prob precompute,
// group-batched loads, slim chain. Bit-identical values to round 9.
//  fwd chain/step: dppf+dppi -> align(3 ldexp) -> 2 add + 2 mul (f32)
//  bwd chain/step: 2 mul -> u=qlo+skip*qhi -> dppf+dppi -> align -> 2 add
//  renorm (every 8 steps): lane-local exponent extract + 2 ldexp (no x-lane).
// Wave 0: forward alpha_255 (t=0..255). Wave 1: backward beta_255 (t=511..256).
// loglik = log2(sum_s alpha_255[s]*beta_255[s]) + ca + cb.
// Lane l holds extended states {2l, 2l+1}; S=97 -> lanes 0..48 live.

constexpr int Bc = 512, Tc = 512, Cc = 128, Lc = 48;
constexpr float FEPS = 1e-7f;
constexpr float FNEG = -1e30f;
constexpr float LN2F = 0.69314718055994530942f;
constexpr int CDEAD = -(1 << 28);  // scale of value-dead lanes

#define DPP_WAVE_SHR1 0x138
#define DPP_WAVE_SHL1 0x130

__device__ __forceinline__ float dppf_shr1(float x) {
    // lane l <- lane l-1; lane 0 <- 0.0f
    return __int_as_float(__builtin_amdgcn_update_dpp(
        0, __float_as_int(x), DPP_WAVE_SHR1, 0xF, 0xF, false));
}
__device__ __forceinline__ float dppf_shl1(float x) {
    // lane l <- lane l+1; lane 63 <- 0.0f
    return __int_as_float(__builtin_amdgcn_update_dpp(
        0, __float_as_int(x), DPP_WAVE_SHL1, 0xF, 0xF, false));
}
__device__ __forceinline__ int dppi_shr1_self(int c) {
    // lane l <- lane l-1; lane 0 <- own c
    return __builtin_amdgcn_update_dpp(c, c, DPP_WAVE_SHR1, 0xF, 0xF, false);
}
__device__ __forceinline__ int dppi_shl1_self(int c) {
    return __builtin_amdgcn_update_dpp(c, c, DPP_WAVE_SHL1, 0xF, 0xF, false);
}

__device__ __forceinline__ float lae2(float a, float b) {  // final reduce only
    float m = fmaxf(a, b);
    float d = fabsf(a - b);
    return m + __log2f(1.0f + __builtin_amdgcn_exp2f(-d));
}
__device__ __forceinline__ float rd63f(float v) {
    return __uint_as_float((unsigned)
        __builtin_amdgcn_readlane(__float_as_uint(v), 63));
}

__global__ __launch_bounds__(128)
void ctc_fb_kernel(const int* __restrict__ y_true,
                   const float* __restrict__ y_pred,
                   float* __restrict__ out) {
    const int b = blockIdx.x;
    const int lane = threadIdx.x & 63;
    const int wave = threadIdx.x >> 6;

    const float* yb = y_pred + (size_t)b * Tc * Cc;

    const int lab = (lane < Lc) ? y_true[b * Lc + lane] : (Cc - 1);
    const int labm1 = __builtin_amdgcn_ds_bpermute(((lane + 63) & 63) << 2, lab);
    const bool skip  = (lab != (Cc - 1)) && (lab != labm1);   // into 2l+1 from 2l-1
    const bool validhi = (lane < Lc);
    const bool lane0 = (lane == 0);

    __shared__ float sblo[64], sbhi[64];
    __shared__ int sbc[64];

    float lo = 0.0f, hi = 0.0f;
    int c = CDEAD;   // per-lane log2 scale (exact integer)

    auto renorm = [&]() {   // lane-local, every 8 steps (R9 cadence)
        float mx = fmaxf(lo, hi);
        int e = (int)((__float_as_uint(mx) >> 23) & 0xFF) - 127;
        e = (mx > 0.0f) ? e : 0;           // value-0 lanes: scale unchanged
        lo = ldexpf(lo, -e);
        hi = ldexpf(hi, -e);
        c += e;
    };

    float praw[16], pbf[16], phf[16];
    auto batch = [&]() {   // off-chain prob prep (bit-identical values to R9)
        #pragma unroll
        for (int j = 0; j < 16; ++j) {
            pbf[j] = rd63f(praw[j]) + FEPS;
            phf[j] = validhi ? (praw[j] + FEPS) : 0.0f;
        }
    };

    if (wave == 0) {
        // -------- forward: alpha_255, consume p_0..p_255 --------
        auto step = [&](int j) {
            float sh  = dppf_shr1(hi);       // alpha[2l-1] (value)
            int   cm1 = dppi_shr1_self(c);   // its scale
            bool  own_dead = (lo == 0.0f) && (hi == 0.0f);
            int   m  = own_dead ? cm1 : ((c > cm1) ? c : cm1);
            float lov = ldexpf(lo, c - m);
            float hiv = ldexpf(hi, c - m);
            float shv = ldexpf(sh, cm1 - m);
            float a3  = skip ? shv : 0.0f;
            lo = (lov + shv) * pbf[j];       // even state (blank)
            hi = (hiv + lov + a3) * phf[j];  // odd state (label)
            c = m;
        };
        #pragma unroll
        for (int j = 0; j < 16; ++j) praw[j] = yb[j * Cc + lab];
        {   // group 0 (t=0..15), init at t=0
            batch();
            const float* ybn = yb + (size_t)16 * Cc + lab;
            #pragma unroll
            for (int j = 0; j < 16; ++j) praw[j] = ybn[(size_t)j * Cc];
            lo = lane0 ? pbf[0] : 0.0f;      // state 0 = blank
            hi = lane0 ? phf[0] : 0.0f;      // state 1 = label[0]
            c  = lane0 ? 0 : CDEAD;
            #pragma unroll
            for (int j = 1; j < 16; ++j) {
                step(j);
                if (j == 7 || j == 15) renorm();
            }
        }
        #pragma unroll 1
        for (int g = 1; g < 16; ++g) {
            batch();
            if (g < 15) {
                const float* ybn = yb + (size_t)((g + 1) * 16) * Cc + lab;
                #pragma unroll
                for (int j = 0; j < 16; ++j) praw[j] = ybn[(size_t)j * Cc];
            }
            #pragma unroll
            for (int j = 0; j < 16; ++j) {
                step(j);
                if (j == 7 || j == 15) renorm();
            }
        }
    } else {
        // -------- backward: beta_255, consume p_511..p_256 --------
        // q[s] = beta_{t+1}[s] * p_{t+1}[s]
        // beta_t[2l]   = q[2l] + q[2l+1]
        // beta_t[2l+1] = q[2l+1] + shl1( q[2l] + (skip ? q[2l+1] : 0) )
        auto step = [&](int j) {
            float qlo = lo * pbf[j];             // q[2l]
            float qhi = hi * phf[j];             // q[2l+1]
            float u   = qlo + (skip ? qhi : 0.0f);
            float un  = dppf_shl1(u);            // lane l+1's contribution
            int   cp1 = dppi_shl1_self(c);
            bool  own_dead = (qlo == 0.0f) && (qhi == 0.0f);
            int   m  = own_dead ? cp1 : ((c > cp1) ? c : cp1);
            lo = ldexpf(qlo + qhi, c - m);
            hi = ldexpf(qhi, c - m) + ldexpf(un, cp1 - m);
            c = m;
        };
        lo = (lane == 48) ? 1.0f : 0.0f;     // beta_511: state 96
        hi = (lane == 47) ? 1.0f : 0.0f;     // beta_511: state 95
        c  = (lane == 47 || lane == 48) ? 0 : CDEAD;
        #pragma unroll
        for (int j = 0; j < 16; ++j) praw[j] = yb[(size_t)(511 - j) * Cc + lab];
        #pragma unroll 1
        for (int g = 0; g < 16; ++g) {
            batch();
            if (g < 15) {
                const float* ybn = yb + lab;
                const int t0 = 511 - (g + 1) * 16;
                #pragma unroll
                for (int j = 0; j < 16; ++j) praw[j] = ybn[(size_t)(t0 - j) * Cc];
            }
            #pragma unroll
            for (int j = 0; j < 16; ++j) {
                step(j);
                if (j == 7 || j == 15) renorm();
            }
        }
        sblo[lane] = lo;
        sbhi[lane] = hi;
        sbc[lane]  = c;
    }

    __syncthreads();

    if (wave == 0) {
        // loglik = log2( sum_s alpha_255[s]*beta_255[s] * 2^(ca+cb) )
        float blo = sblo[lane], bhi = sbhi[lane];
        float ctot = (float)(c + sbc[lane]);
        float plo = lo * blo;
        float phi = hi * bhi;
        float yl = (plo > 0.0f) ? (__log2f(plo) + ctot) : FNEG;
        float yh = (phi > 0.0f) ? (__log2f(phi) + ctot) : FNEG;
        float v = lae2(yl, yh);
        #pragma unroll
        for (int mk = 1; mk < 64; mk <<= 1)
            v = lae2(v, __shfl_xor(v, mk, 64));
        if (lane0) out[b] = -(v * LN2F);
    }
}

extern "C" void kernel_launch(void* const* d_in, const int* in_sizes, int n_in,
                              void* d_out, int out_size, void* d_ws, size_t ws_size,
                              hipStream_t stream) {
    const int* y_true = (const int*)d_in[0];
    const float* y_pred = (const float*)d_in[1];
    float* out = (float*)d_out;
    hipLaunchKernelGGL(ctc_fb_kernel, dim3(Bc), dim3(128), 0, stream,
                       y_true, y_pred, out);
}